// Round 6
// baseline (138.368 us; speedup 1.0000x reference)
//
#include <hip/hip_runtime.h>

#define HH 128
#define WW 128
#define CC 64
#define CO 64
#define BB 4
#define GG 8
#define CG 8
#define KK 9
#define HW (HH*WW)

// LDS tile geometry: 13 rows x 33 px window per group, 4 groups per half
#define TROWS 13
#define TPX   33

typedef __attribute__((ext_vector_type(8))) short short8;
typedef __attribute__((ext_vector_type(4))) float floatx4;
typedef __attribute__((ext_vector_type(2))) float f32x2;

union S8I { short8 s; int i[4]; };
union FU { float f; unsigned u; };

__device__ inline short f2bf(float f) {
    FU v; v.f = f;
    return (short)((v.u + 0x7FFF + ((v.u >> 16) & 1)) >> 16);
}
__device__ inline unsigned rnd2(float f) {   // round-half-up bf16 in bits [31:16]
    FU v; v.f = f;
    return v.u + 0x8000u;
}
__device__ inline float bflo(int e) { union { int i; float f; } u; u.i = e << 16; return u.f; }
__device__ inline float bfhi(int e) { union { int i; float f; } u; u.i = e & 0xffff0000; return u.f; }

// ---- merged prep (unchanged) ----
// A-frag layout for the half-K GEMM: fid = (h*9+gc)*4 + ot,
//   wf[fid*512 + L*8 + j] = bf16(W[o=ot*16+(L&15)][g=h*4+(L>>4)][cg=j][kk=gc])
// Input NCHW f32 -> in_t[b][g][y*W+x][cg] bf16 (16B per pixel-group).
__global__ __launch_bounds__(256)
void prep(const float* __restrict__ wt, const float* __restrict__ in,
          short* __restrict__ wf, short* __restrict__ in_t) {
    const int bid = blockIdx.x;
    if (bid < 144) {
        const int tid = bid * 256 + threadIdx.x;   // < 36864 = 576*64
        const int j   = tid & 7;
        const int L   = (tid >> 3) & 63;
        const int fid = tid >> 9;                  // (h*9+gc)*4 + ot, 0..71
        const int ot  = fid & 3;
        const int gch = fid >> 2;                  // h*9 + gc, 0..17
        const int h   = gch / 9, gc = gch - h * 9;
        const int o   = ot * 16 + (L & 15);
        const int g   = h * 4 + (L >> 4);
        wf[tid] = f2bf(wt[o * 576 + (g * 8 + j) * 9 + gc]);
    } else {
        const int idx = bid - 144;                 // 2048 blocks: 64 x 8 x 4
        const int bx = idx & 63;
        const int g  = (idx >> 6) & 7;
        const int b  = idx >> 9;
        const int p  = bx * 256 + threadIdx.x;
        const float* src = in + (b * CC + g * CG) * HW + p;
        short8 v;
        #pragma unroll
        for (int cg = 0; cg < CG; ++cg) v[cg] = f2bf(src[cg * HW]);
        *(short8*)(in_t + ((b * GG + g) * HW + p) * 8) = v;
    }
}

// v5: LDS-TILE gather. Theory: 5 schedules converged at 43-48us because the
// invariant 18.9M scattered gather lane-addresses saturate the TA (~1 lane/cy
// /CU ~= 31us). Fix: stage a bounded input window in LDS (ds_read_b128 ~0.19
// cy/lane, ~5x TA rate); offsets are N(0,1) so a 13-row x 33-px window covers
// |dy|<=3,|dx|<=7 (~99.9% of corners); rare out-of-window corners take a
// masked global-load fallback (exact semantics preserved).
// Block = 4 rows x 16 px, wave w = row rb+w; lane quad = k-block, so the
// B-frag-direct MFMA identity is unchanged. A-frags from L2-hot global (r0-
// validated; benign since vmcnt stream no longer carries scattered gathers).
// LDS 27.5KB -> 4 blocks/CU co-resident (static occ 50%).
__global__ __launch_bounds__(256, 4)
void dcn_tile(const short* __restrict__ in_t, const float* __restrict__ off,
              const float* __restrict__ msk, const short* __restrict__ wf,
              const float* __restrict__ bias, float* __restrict__ out)
{
    __shared__ short tile[4 * TROWS * TPX * 8];   // 27,456 B

    const int t = threadIdx.x;

    // bijective XCD swizzle (1024 % 8 == 0)
    const int lin = (blockIdx.x & 7) * 128 + (blockIdx.x >> 3);
    const int b   = lin >> 8;          // 0..3
    const int rem = lin & 255;
    const int rq  = rem >> 3;          // 0..31: row-quad
    const int pxg = rem & 7;           // 0..7: 16-px group
    const int rb  = rq << 2;
    const int pxbase = pxg << 4;

    const int w = t >> 6, lane = t & 63;
    const int q4 = lane >> 4, n16 = lane & 15;
    const int row = rb + w;                    // this wave's output row
    const int px  = pxbase + n16;              // this lane's output pixel
    const int basepix = row * WW + px;

    const int ylo = rb - 4;                    // tile window origin (may be <0)
    const int xlo = pxbase - 8;

    floatx4 acc[4];
    #pragma unroll
    for (int ot = 0; ot < 4; ++ot)
        #pragma unroll
        for (int r = 0; r < 4; ++r)
            acc[ot][r] = bias[ot * 16 + q4 * 4 + r];

    const char* ib = (const char*)(in_t + (long)b * GG * HW * 8);

    #pragma unroll
    for (int h = 0; h < 2; ++h) {
        // ---- stage this half's tile: 4 groups x 13 rows x 33 px x 16B ----
        if (h) __syncthreads();        // all waves done reading half-0 tile
        #pragma unroll
        for (int it = 0; it < 7; ++it) {
            const int s = it * 256 + t;        // 1716 slots total
            if (s < 4 * TROWS * TPX) {
                const int gl = s / (TROWS * TPX);
                const int r2 = s - gl * (TROWS * TPX);
                const int rs = r2 / TPX;
                const int xs = r2 - rs * TPX;
                const int y  = min(max(ylo + rs, 0), HH - 1);
                const int x  = min(max(xlo + xs, 0), WW - 1);
                const int g  = h * 4 + gl;
                const short8 v = *(const short8*)(ib + (g << 18) + (y << 11) + (x << 4));
                *(short8*)(tile + ((gl * TROWS + rs) * TPX + xs) * 8) = v;
            }
        }
        __syncthreads();

        const int g   = h * 4 + q4;    // per-LANE offset group (B-frag k-block)
        const int gsh = g << 18;

        // ---- preload off/mask: 27 independent coalesced loads ----
        float pdy[9], pdx[9], pm[9];
        #pragma unroll
        for (int i = 0; i < 9; ++i) {
            const int offc = (b * 144 + g * 18 + i * 2) * HW + basepix;
            pdy[i] = off[offc];
            pdx[i] = off[offc + HW];
            pm[i]  = msk[(b * 72 + g * 9 + i) * HW + basepix];
        }

        // ---- 3 fenced batches of 3 taps; gathers now hit LDS ----
        #pragma unroll
        for (int q = 0; q < 3; ++q) {
            const int i0 = q * 3;
            S8I u00[3], u01[3], u10[3], u11[3];
            float cw00[3], cw01[3], cw10[3], cw11[3];

            #pragma unroll
            for (int j = 0; j < 3; ++j) {
                const int i = i0 + j;
                const int ky = i / 3, kx = i - (i / 3) * 3;   // consts

                const float py  = (float)(row - 1 + ky) + pdy[i];
                const float pxf = (float)(px - 1 + kx) + pdx[i];
                const float y0f = floorf(py), x0f = floorf(pxf);
                const float ly = py - y0f, lx = pxf - x0f;
                const int y0 = (int)y0f, x0 = (int)x0f;
                const int y1 = y0 + 1,  x1 = x0 + 1;

                const float vy0 = (y0 >= 0 && y0 < HH) ? 1.f : 0.f;
                const float vy1 = (y1 >= 0 && y1 < HH) ? 1.f : 0.f;
                const float vx0 = (x0 >= 0 && x0 < WW) ? 1.f : 0.f;
                const float vx1 = (x1 >= 0 && x1 < WW) ? 1.f : 0.f;
                const int y0c = min(max(y0, 0), HH - 1), y1c = min(max(y1, 0), HH - 1);
                const int x0c = min(max(x0, 0), WW - 1), x1c = min(max(x1, 0), WW - 1);

                const float m = pm[i];
                const float wy0 = (1.f - ly) * vy0 * m;
                const float wy1 = ly * vy1 * m;
                const float wx0 = (1.f - lx) * vx0;
                const float wx1 = lx * vx1;
                cw00[j] = wy0 * wx0; cw01[j] = wy0 * wx1;
                cw10[j] = wy1 * wx0; cw11[j] = wy1 * wx1;

                // window-relative slots (unsigned trick: <0 or >max both fail)
                const int ys0r = y0c - ylo, ys1r = y1c - ylo;
                const int xs0r = x0c - xlo, xs1r = x1c - xlo;
                const bool iy0 = (unsigned)ys0r <= (TROWS - 1u);
                const bool iy1 = (unsigned)ys1r <= (TROWS - 1u);
                const bool ix0 = (unsigned)xs0r <= (TPX - 1u);
                const bool ix1 = (unsigned)xs1r <= (TPX - 1u);
                const int ys0 = min(max(ys0r, 0), TROWS - 1);
                const int ys1 = min(max(ys1r, 0), TROWS - 1);
                const int xs0 = min(max(xs0r, 0), TPX - 1);
                const int xs1 = min(max(xs1r, 0), TPX - 1);

                const int gbase = q4 * (TROWS * TPX);
                u00[j].s = *(const short8*)(tile + ((gbase + ys0 * TPX + xs0)) * 8);
                u01[j].s = *(const short8*)(tile + ((gbase + ys0 * TPX + xs1)) * 8);
                u10[j].s = *(const short8*)(tile + ((gbase + ys1 * TPX + xs0)) * 8);
                u11[j].s = *(const short8*)(tile + ((gbase + ys1 * TPX + xs1)) * 8);

                // rare fallback: out-of-window corner with nonzero weight
                if (__builtin_expect(!(iy0 && ix0) && cw00[j] != 0.f, 0))
                    u00[j].s = *(const short8*)(ib + gsh + (y0c << 11) + (x0c << 4));
                if (__builtin_expect(!(iy0 && ix1) && cw01[j] != 0.f, 0))
                    u01[j].s = *(const short8*)(ib + gsh + (y0c << 11) + (x1c << 4));
                if (__builtin_expect(!(iy1 && ix0) && cw10[j] != 0.f, 0))
                    u10[j].s = *(const short8*)(ib + gsh + (y1c << 11) + (x0c << 4));
                if (__builtin_expect(!(iy1 && ix1) && cw11[j] != 0.f, 0))
                    u11[j].s = *(const short8*)(ib + gsh + (y1c << 11) + (x1c << 4));
            }

            __builtin_amdgcn_sched_barrier(0);

            #pragma unroll
            for (int j = 0; j < 3; ++j) {
                const int i = i0 + j;
                const f32x2 W00 = {cw00[j], cw00[j]}, W01 = {cw01[j], cw01[j]};
                const f32x2 W10 = {cw10[j], cw10[j]}, W11 = {cw11[j], cw11[j]};
                S8I res;
                #pragma unroll
                for (int pc = 0; pc < 4; ++pc) {
                    const int e00 = u00[j].i[pc], e01 = u01[j].i[pc];
                    const int e10 = u10[j].i[pc], e11 = u11[j].i[pc];
                    f32x2 a00 = {bflo(e00), bfhi(e00)};
                    f32x2 a01 = {bflo(e01), bfhi(e01)};
                    f32x2 a10 = {bflo(e10), bfhi(e10)};
                    f32x2 a11 = {bflo(e11), bfhi(e11)};
                    f32x2 v = a00 * W00;
                    v += a01 * W01;
                    v += a10 * W10;
                    v += a11 * W11;
                    res.i[pc] = (int)__builtin_amdgcn_perm(rnd2(v.y), rnd2(v.x), 0x07060302u);
                }

                // res.s IS the B-fragment for chunk (h,i); A-frags L2-hot global
                #pragma unroll
                for (int ot = 0; ot < 4; ++ot) {
                    const short8 afr = *(const short8*)&wf[((h * 9 + i) * 4 + ot) * 512 + lane * 8];
                    acc[ot] = __builtin_amdgcn_mfma_f32_16x16x32_bf16(afr, res.s, acc[ot], 0, 0, 0);
                }
            }
        }
    }

    // ---- epilogue: o = ot*16 + q4*4 + r ----
    #pragma unroll
    for (int ot = 0; ot < 4; ++ot)
        #pragma unroll
        for (int r = 0; r < 4; ++r)
            out[((b * CO + ot * 16 + q4 * 4 + r) * HH + row) * WW + px] = acc[ot][r];
}

extern "C" void kernel_launch(void* const* d_in, const int* in_sizes, int n_in,
                              void* d_out, int out_size, void* d_ws, size_t ws_size,
                              hipStream_t stream) {
    const float* in   = (const float*)d_in[0];
    const float* off  = (const float*)d_in[1];
    const float* msk  = (const float*)d_in[2];
    const float* wt   = (const float*)d_in[3];
    const float* bias = (const float*)d_in[4];
    float* out = (float*)d_out;
    short* wf   = (short*)d_ws;            // 36864 shorts = 72 KB
    short* in_t = (short*)d_ws + 36864;    // 4*8*16384*8 shorts = 8 MB

    prep<<<144 + 2048, 256, 0, stream>>>(wt, in, wf, in_t);

    dcn_tile<<<1024, 256, 0, stream>>>(in_t, off, msk, wf, bias, out);
}